// Round 8
// baseline (140.238 us; speedup 1.0000x reference)
//
#include <hip/hip_runtime.h>
#include <stdint.h>

// SparseConv3d bf16-MFMA implicit GEMM. B=2, Cin=32, Cout=64, D=64, K=3.
// Round 8: barrier-free, LDS-free conv. Every wave independent:
//   wave = 4y x 32x x 64co, 432 MFMA : 108 B-loads : 108 A-loads, all direct
//   from global (L1/L2 serve reuse). xt stored PADDED (66 y-rows, 66 x-slots,
//   zeros in pads) so the inner loop has zero boundary logic; z-OOB planes
//   skipped by wave-uniform branch. Grid 512 blocks x 4 waves = 2 blocks/CU.
// xt layout: [b][zz(64)][yy(66 padded)] rows of 66 x-slots * 64B;
//   elem (sx, ci) at u16 pos sx*32 + ci  (sx = x+1, plain channel-last).

#define DD 64
#define CIN 32
#define COUT 64

typedef __bf16 bf16x8 __attribute__((ext_vector_type(8)));
typedef float f32x16 __attribute__((ext_vector_type(16)));

#define ROW_U16   2112u                                // 66 slots * 32 ci
#define XT_U16    ((size_t)2 * 64 * 66 * ROW_U16)      // 17,842,176
#define XT_BYTES  (XT_U16 * 2)                         // 35,684,352
#define WPK_U16   (27 * 2 * 2 * 64 * 8)                // 55,296
#define WS_NEEDED (XT_BYTES + (size_t)WPK_U16 * 2)

__device__ __forceinline__ uint16_t f2bf(float f) {
    uint32_t u = __builtin_bit_cast(uint32_t, f);
    u += 0x7fffu + ((u >> 16) & 1u);   // RNE
    return (uint16_t)(u >> 16);
}

// ---------------- pre-kernel 1: weight pack ----------------
// wpk flat: (((k27*2 + cb)*2 + ct)*64 + lane)*8 + j
//   lane holds A[co = ct*32 + (lane&31)][ci = cb*16 + (lane>>5)*8 + j]
__global__ void pack_weights(const float* __restrict__ w, uint16_t* __restrict__ wpk) {
    int flat = blockIdx.x * 256 + threadIdx.x;
    if (flat >= WPK_U16) return;
    int j   = flat & 7;
    int l   = (flat >> 3) & 63;
    int ct  = (flat >> 9) & 1;
    int cb  = (flat >> 10) & 1;
    int k27 = flat >> 11;
    int co = ct * 32 + (l & 31);
    int ci = cb * 16 + ((l >> 5) * 8) + j;
    wpk[flat] = f2bf(w[(co * CIN + ci) * 27 + k27]);
}

// ---------------- pre-kernel 2: x -> padded channel-last bf16 ----------------
// grid (66, 64, 2): one (b, z, yy) padded row per block. yy=0 and 65 are zero
// rows; interior rows get zero slots at sx=0 and sx=65.
__global__ __launch_bounds__(256)
void transpose_x(const float* __restrict__ x, uint16_t* __restrict__ xt) {
    __shared__ uint16_t tile[ROW_U16];
    const int yy = blockIdx.x, z = blockIdx.y, b = blockIdx.z;
    const int y = yy - 1;
    const int t = threadIdx.x;
    uint4* dst = (uint4*)(xt + ((size_t)(b * DD + z) * 66 + yy) * ROW_U16);

    if (y < 0 || y >= DD) {
        for (int i = t; i < 264; i += 256) dst[i] = make_uint4(0, 0, 0, 0);
        return;
    }
    const int ci = t >> 3;
    const int xs = (t & 7) * 8;
    const float* src = x + ((((size_t)b * CIN + ci) * DD + z) * DD + y) * DD + xs;
    float4 v0 = *(const float4*)src;
    float4 v1 = *(const float4*)(src + 4);
    float vals[8] = {v0.x, v0.y, v0.z, v0.w, v1.x, v1.y, v1.z, v1.w};
#pragma unroll
    for (int e = 0; e < 8; ++e)
        tile[(xs + e + 1) * 32 + ci] = f2bf(vals[e]);
    if (t < 32) { tile[t] = 0; tile[65 * 32 + t] = 0; }   // x-pad slots
    __syncthreads();
    for (int i = t; i < 264; i += 256) dst[i] = ((const uint4*)tile)[i];
}

// ---------------- main kernel: barrier-free MFMA conv ----------------
// grid (8, 64, 2) x 256 thr; wave w: xtile = w&1, yqh = w>>1;
// y0 = (blockIdx.x*2 + yqh)*4. Wave: 4y x 32x x 64co, fully independent.
__global__ __launch_bounds__(256, 2)
void conv_mfma(const uint16_t* __restrict__ xt, const uint16_t* __restrict__ wpk,
               const int* __restrict__ mask, const float* __restrict__ bias,
               float* __restrict__ out) {
    const int yo = blockIdx.x, z = blockIdx.y, b = blockIdx.z;
    const int tid = threadIdx.x;
    const int lane = tid & 63;
    const int w = __builtin_amdgcn_readfirstlane(tid >> 6);
    const int xtile = w & 1;
    const int y0 = (yo * 2 + (w >> 1)) * 4;
    const int u = lane & 31;
    const int h = lane >> 5;
    const int xoff = xtile * 32;

    f32x16 acc[4][2];   // [ly][ct]
#pragma unroll
    for (int ly = 0; ly < 4; ++ly)
#pragma unroll
        for (int ct = 0; ct < 2; ++ct)
#pragma unroll
            for (int i = 0; i < 16; ++i) acc[ly][ct][i] = 0.f;

    for (int p = 0; p < 3; ++p) {
        const int zz = z - 1 + p;
        if (zz < 0 || zz >= DD) continue;          // wave-uniform skip (z pad)
        const uint16_t* plane = xt + (size_t)(b * DD + zz) * 66 * ROW_U16;
#pragma unroll
        for (int cb = 0; cb < 2; ++cb) {
            bf16x8 wf[9][2];
#pragma unroll
            for (int q = 0; q < 9; ++q) {
                const int k27 = p * 9 + q;
                wf[q][0] = *(const bf16x8*)(wpk + (size_t)((k27 * 2 + cb) * 2 + 0) * 512 + lane * 8);
                wf[q][1] = *(const bf16x8*)(wpk + (size_t)((k27 * 2 + cb) * 2 + 1) * 512 + lane * 8);
            }
            const unsigned chunk = (unsigned)((cb * 2 + h) * 8);
#pragma unroll
            for (int t = 0; t < 6; ++t) {
                // padded row: real yy = y0-1+t -> padded idx y0+t (always in [0,65])
                const uint16_t* rowp = plane + (size_t)(y0 + t) * ROW_U16 + chunk;
                bf16x8 bf[3];
#pragma unroll
                for (int kx = 0; kx < 3; ++kx)
                    bf[kx] = *(const bf16x8*)(rowp + (unsigned)(xoff + u + kx) * 32);
#pragma unroll
                for (int kx = 0; kx < 3; ++kx) {
#pragma unroll
                    for (int ly = 0; ly < 4; ++ly) {
                        const int ky = t - ly;
                        if (ky >= 0 && ky < 3) {
                            acc[ly][0] = __builtin_amdgcn_mfma_f32_32x32x16_bf16(
                                wf[ky * 3 + kx][0], bf[kx], acc[ly][0], 0, 0, 0);
                            acc[ly][1] = __builtin_amdgcn_mfma_f32_32x32x16_bf16(
                                wf[ky * 3 + kx][1], bf[kx], acc[ly][1], 0, 0, 0);
                        }
                    }
                }
            }
        }
    }

    // ---- epilogue: +bias, x mask, store. C: col = u (x), row = (r&3)+8*(r>>2)+4*h (co) ----
    const size_t mb = (((size_t)b * DD + z) * DD + y0) * DD + xoff + u;
    float m[4];
#pragma unroll
    for (int ly = 0; ly < 4; ++ly) m[ly] = mask[mb + ly * DD] ? 1.0f : 0.0f;
#pragma unroll
    for (int r = 0; r < 16; ++r) {
#pragma unroll
        for (int ct = 0; ct < 2; ++ct) {
            const int co = ct * 32 + (r & 3) + 8 * (r >> 2) + 4 * h;
            const float bs = bias[co];
            const size_t o = ((size_t)b * COUT + co) * (DD * DD * DD)
                           + (size_t)z * (DD * DD) + (size_t)y0 * DD + xoff + u;
#pragma unroll
            for (int ly = 0; ly < 4; ++ly)
                out[o + ly * DD] = (acc[ly][ct][r] + bs) * m[ly];
        }
    }
}

// ---------------- fp32 fallback (ws too small) ----------------
#define CI_BLK 16
__global__ __launch_bounds__(256, 2)
void sparse_conv3d_f32(const float* __restrict__ x,
                       const int* __restrict__ mask,
                       const float* __restrict__ weight,
                       const float* __restrict__ bias,
                       float* __restrict__ out) {
    __shared__ float lds[9 * CI_BLK * 66];
    const int y = blockIdx.x, z = blockIdx.y, b = blockIdx.z;
    const int lane = threadIdx.x & 63;
    const int wave = __builtin_amdgcn_readfirstlane(threadIdx.x >> 6);
    float acc[16];
#pragma unroll
    for (int j = 0; j < 16; ++j) acc[j] = 0.0f;
    const int co0 = wave * 16;
    const float* wbase = weight + (size_t)co0 * (CIN * 27);
    for (int cbl = 0; cbl < 2; ++cbl) {
        if (cbl) __syncthreads();
        for (int i = wave; i < 9 * CI_BLK; i += 4) {
            const int r = i >> 4, ci_l = i & 15;
            const int zz = z + (r / 3) - 1, yy = y + (r % 3) - 1;
            const int ci = cbl * CI_BLK + ci_l;
            float v = 0.0f;
            if (zz >= 0 && zz < DD && yy >= 0 && yy < DD)
                v = x[((((size_t)b * CIN + ci) * DD + zz) * DD + yy) * DD + lane];
            float* row = &lds[(size_t)i * 66];
            row[1 + lane] = v;
            if (lane == 0) { row[0] = 0.0f; row[65] = 0.0f; }
        }
        __syncthreads();
        for (int ci_l = 0; ci_l < CI_BLK; ++ci_l) {
            const int ci = cbl * CI_BLK + ci_l;
#pragma unroll
            for (int kz = 0; kz < 3; ++kz) {
#pragma unroll
                for (int ky = 0; ky < 3; ++ky) {
                    const int r = kz * 3 + ky;
                    const float* xrow = &lds[(size_t)(r * CI_BLK + ci_l) * 66 + lane];
                    const float xv0 = xrow[0], xv1 = xrow[1], xv2 = xrow[2];
                    const float* wp = wbase + ci * 27 + kz * 9 + ky * 3;
#pragma unroll
                    for (int j = 0; j < 16; ++j) {
                        acc[j] += wp[(size_t)j * (CIN * 27) + 0] * xv0
                                + wp[(size_t)j * (CIN * 27) + 1] * xv1
                                + wp[(size_t)j * (CIN * 27) + 2] * xv2;
                    }
                }
            }
        }
    }
    const float m = mask[(((size_t)b * DD + z) * DD + y) * DD + lane] ? 1.0f : 0.0f;
#pragma unroll
    for (int j = 0; j < 16; ++j) {
        const int co = co0 + j;
        out[((((size_t)b * COUT + co) * DD + z) * DD + y) * DD + lane] = (acc[j] + bias[co]) * m;
    }
}
#undef CI_BLK

extern "C" void kernel_launch(void* const* d_in, const int* in_sizes, int n_in,
                              void* d_out, int out_size, void* d_ws, size_t ws_size,
                              hipStream_t stream) {
    const float* x    = (const float*)d_in[0];
    const int*   mask = (const int*)d_in[1];
    const float* w    = (const float*)d_in[2];
    const float* bias = (const float*)d_in[3];
    float*       out  = (float*)d_out;

    if (ws_size < WS_NEEDED) {
        sparse_conv3d_f32<<<dim3(DD, DD, 2), 256, 0, stream>>>(x, mask, w, bias, out);
        return;
    }

    uint16_t* xt  = (uint16_t*)d_ws;
    uint16_t* wpk = (uint16_t*)((char*)d_ws + XT_BYTES);

    pack_weights<<<(WPK_U16 + 255) / 256, 256, 0, stream>>>(w, wpk);
    transpose_x<<<dim3(66, DD, 2), 256, 0, stream>>>(x, xt);
    conv_mfma<<<dim3(DD / 8, DD, 2), 256, 0, stream>>>(xt, wpk, mask, bias, out);
}